// Round 2
// baseline (1368.729 us; speedup 1.0000x reference)
//
#include <hip/hip_runtime.h>

#define N_NODES  100000
#define N_EDGES  1600000
#define N_GRAPHS 512
#define DIM      128
#define EDGE_DIM 16
#define BN_EPS   1e-5f

// ============================ CSR build ============================

__global__ __launch_bounds__(256) void k_hist(const int* __restrict__ dst,
                                              int* __restrict__ deg) {
    int e = blockIdx.x * 256 + threadIdx.x;
    if (e < N_EDGES) atomicAdd(&deg[dst[e]], 1);
}

// inclusive scan of 1024-elem chunks; writes scanned chunk into rowptr+1, chunk total into sums
__global__ __launch_bounds__(256) void k_scan1(const int* __restrict__ deg,
                                               int* __restrict__ rowptr1,
                                               int* __restrict__ sums, int N) {
    __shared__ int sc[256];
    int t = threadIdx.x;
    int base = blockIdx.x * 1024 + t * 4;
    int v0 = (base + 0 < N) ? deg[base + 0] : 0;
    int v1 = (base + 1 < N) ? deg[base + 1] : 0;
    int v2 = (base + 2 < N) ? deg[base + 2] : 0;
    int v3 = (base + 3 < N) ? deg[base + 3] : 0;
    v1 += v0; v2 += v1; v3 += v2;
    sc[t] = v3;
    __syncthreads();
    for (int o = 1; o < 256; o <<= 1) {
        int add = (t >= o) ? sc[t - o] : 0;
        __syncthreads();
        sc[t] += add;
        __syncthreads();
    }
    int prefix = sc[t] - v3;       // exclusive prefix of this thread's 4 elems
    if (base + 0 < N) rowptr1[base + 0] = v0 + prefix;
    if (base + 1 < N) rowptr1[base + 1] = v1 + prefix;
    if (base + 2 < N) rowptr1[base + 2] = v2 + prefix;
    if (base + 3 < N) rowptr1[base + 3] = v3 + prefix;
    if (t == 255) sums[blockIdx.x] = sc[255];
}

__global__ __launch_bounds__(256) void k_scan2(int* __restrict__ sums, int n) {
    __shared__ int sc[256];
    int t = threadIdx.x;
    int v = (t < n) ? sums[t] : 0;
    sc[t] = v;
    __syncthreads();
    for (int o = 1; o < 256; o <<= 1) {
        int add = (t >= o) ? sc[t - o] : 0;
        __syncthreads();
        sc[t] += add;
        __syncthreads();
    }
    if (t < n) sums[t] = sc[t];    // inclusive scan of chunk totals
}

// add chunk offsets; also produce cursor[] = row start for fill phase
__global__ __launch_bounds__(256) void k_scan3(int* __restrict__ rowptr,
                                               int* __restrict__ cursor,
                                               const int* __restrict__ sums, int N) {
    int c = blockIdx.x;
    int off = (c == 0) ? 0 : sums[c - 1];
    int t = threadIdx.x;
    int base = c * 1024 + t * 4;
#pragma unroll
    for (int i = 0; i < 4; i++) {
        int g = base + i;
        if (g < N) {
            int val = rowptr[1 + g] + off;
            rowptr[1 + g] = val;           // rowptr[g+1] = inclusive sum = start of node g+1
            if (g + 1 < N) cursor[g + 1] = val;
        }
    }
    if (c == 0 && t == 0) { rowptr[0] = 0; cursor[0] = 0; }
}

__global__ __launch_bounds__(256) void k_fill(const int* __restrict__ src,
                                              const int* __restrict__ dst,
                                              int* __restrict__ cursor,
                                              int2* __restrict__ csr) {
    int e = blockIdx.x * 256 + threadIdx.x;
    if (e < N_EDGES) {
        int d = dst[e];
        int p = atomicAdd(&cursor[d], 1);
        csr[p] = make_int2(src[e], e);
    }
}

// ==================== GINE message + aggregate ====================
// One wave (64 lanes) per node; lane owns features {lane, lane+64}.
// agg[node] = x[node] + sum_e relu(x[src_e] + edge_attr_e @ le_w + le_b)
__global__ __launch_bounds__(256) void k_gine_msg(const float* __restrict__ x,
                                                  const float* __restrict__ edge_attr,
                                                  const int* __restrict__ rowptr,
                                                  const int2* __restrict__ csr,
                                                  const float* __restrict__ lew,
                                                  const float* __restrict__ leb,
                                                  float* __restrict__ agg) {
    int lane = threadIdx.x & 63;
    int node = blockIdx.x * 4 + (threadIdx.x >> 6);
    if (node >= N_NODES) return;

    float wl0[EDGE_DIM], wl1[EDGE_DIM];
#pragma unroll
    for (int k = 0; k < EDGE_DIM; k++) {
        wl0[k] = lew[k * DIM + lane];
        wl1[k] = lew[k * DIM + 64 + lane];
    }
    float b0 = leb[lane], b1 = leb[64 + lane];

    float acc0 = x[(size_t)node * DIM + lane];
    float acc1 = x[(size_t)node * DIM + 64 + lane];

    int pbeg = rowptr[node], pend = rowptr[node + 1];
    for (int p = pbeg; p < pend; p++) {
        int2 se = csr[p];
        int srcn = __builtin_amdgcn_readfirstlane(se.x);
        int eid  = __builtin_amdgcn_readfirstlane(se.y);
        const float* ea = edge_attr + (size_t)eid * EDGE_DIM;
        float e0 = b0, e1 = b1;
#pragma unroll
        for (int k = 0; k < EDGE_DIM; k++) {
            float a = ea[k];
            e0 += a * wl0[k];
            e1 += a * wl1[k];
        }
        const float* xs = x + (size_t)srcn * DIM;
        float m0 = xs[lane] + e0;       m0 = m0 > 0.f ? m0 : 0.f;
        float m1 = xs[64 + lane] + e1;  m1 = m1 > 0.f ? m1 : 0.f;
        acc0 += m0;
        acc1 += m1;
    }
    agg[(size_t)node * DIM + lane]      = acc0;
    agg[(size_t)node * DIM + 64 + lane] = acc1;
}

// ======================= node GEMM (M x 128 @ 128 x 128) =======================
// MODE 0: out = A @ W + bias                      (pre-BN hidden)
// MODE 1: out = relu( relu(a*A+c) @ W + bias )    (BN-affine+relu in, relu out)
template <int MODE>
__global__ __launch_bounds__(256) void k_gemm(const float* __restrict__ A,
                                              const float* __restrict__ W,
                                              const float* __restrict__ bias,
                                              const float* __restrict__ coef,
                                              float* __restrict__ out, int M) {
    __shared__ float As[32][DIM];
    int t = threadIdx.x;
    int rbase = blockIdx.x * 32;

#pragma unroll
    for (int i = 0; i < 16; i++) {
        int idx = t + i * 256;              // 0..4095
        int r = idx >> 7, c = idx & 127;
        int gr = rbase + r;
        float v = (gr < M) ? A[(size_t)gr * DIM + c] : 0.f;
        if (MODE == 1) {
            v = coef[c] * v + coef[DIM + c];
            v = v > 0.f ? v : 0.f;
        }
        As[r][c] = v;
    }
    __syncthreads();

    int cq = (t & 31) * 4;          // 4 consecutive cols
    int rg = (t >> 5) * 4;          // 4 consecutive rows
    float acc[4][4] = {{0.f}};

    for (int k = 0; k < DIM; k++) {
        float4 w = *(const float4*)&W[(size_t)k * DIM + cq];
        float a0 = As[rg + 0][k], a1 = As[rg + 1][k];
        float a2 = As[rg + 2][k], a3 = As[rg + 3][k];
        acc[0][0] += a0 * w.x; acc[0][1] += a0 * w.y; acc[0][2] += a0 * w.z; acc[0][3] += a0 * w.w;
        acc[1][0] += a1 * w.x; acc[1][1] += a1 * w.y; acc[1][2] += a1 * w.z; acc[1][3] += a1 * w.w;
        acc[2][0] += a2 * w.x; acc[2][1] += a2 * w.y; acc[2][2] += a2 * w.z; acc[2][3] += a2 * w.w;
        acc[3][0] += a3 * w.x; acc[3][1] += a3 * w.y; acc[3][2] += a3 * w.z; acc[3][3] += a3 * w.w;
    }

    float4 bb = *(const float4*)&bias[cq];
#pragma unroll
    for (int i = 0; i < 4; i++) {
        int gr = rbase + rg + i;
        if (gr < M) {
            float4 o;
            o.x = acc[i][0] + bb.x;
            o.y = acc[i][1] + bb.y;
            o.z = acc[i][2] + bb.z;
            o.w = acc[i][3] + bb.w;
            if (MODE == 1) {
                o.x = o.x > 0.f ? o.x : 0.f;
                o.y = o.y > 0.f ? o.y : 0.f;
                o.z = o.z > 0.f ? o.z : 0.f;
                o.w = o.w > 0.f ? o.w : 0.f;
            }
            *(float4*)&out[(size_t)gr * DIM + cq] = o;
        }
    }
}

// ===================== BN column statistics =====================
__global__ __launch_bounds__(128) void k_colstats(const float* __restrict__ h,
                                                  float* __restrict__ colstat, int M) {
    int c = threadIdx.x;
    float s = 0.f, ss = 0.f;
    for (int r = blockIdx.x; r < M; r += gridDim.x) {
        float v = h[(size_t)r * DIM + c];
        s += v;
        ss += v * v;
    }
    atomicAdd(&colstat[c], s);
    atomicAdd(&colstat[DIM + c], ss);
}

__global__ __launch_bounds__(128) void k_bncoef(const float* __restrict__ colstat,
                                                const float* __restrict__ gamma,
                                                const float* __restrict__ beta,
                                                float* __restrict__ coef) {
    int c = threadIdx.x;
    float inv_n = 1.f / (float)N_NODES;
    float mean = colstat[c] * inv_n;
    float var = colstat[DIM + c] * inv_n - mean * mean;
    float a = gamma[c] * rsqrtf(var + BN_EPS);
    coef[c] = a;
    coef[DIM + c] = beta[c] - mean * a;
}

// ===================== global add pool (batch is sorted) =====================
__global__ __launch_bounds__(128) void k_pool(const float* __restrict__ h,
                                              const int* __restrict__ batch,
                                              float* __restrict__ pooled) {
    int g = blockIdx.x;
    int c = threadIdx.x;
    int lo = 0, hi = N_NODES;
    while (lo < hi) { int mid = (lo + hi) >> 1; if (batch[mid] < g) lo = mid + 1; else hi = mid; }
    int start = lo;
    hi = N_NODES;
    while (lo < hi) { int mid = (lo + hi) >> 1; if (batch[mid] < g + 1) lo = mid + 1; else hi = mid; }
    int end = lo;
    float s = 0.f;
    for (int n = start; n < end; n++) s += h[(size_t)n * DIM + c];
    pooled[g * DIM + c] = s;
}

// ===================== classifier: relu(p@Wc1+bc1)@Wc2+bc2 =====================
__global__ __launch_bounds__(64) void k_cls(const float* __restrict__ pooled,
                                            const float* __restrict__ Wc1,
                                            const float* __restrict__ bc1,
                                            const float* __restrict__ Wc2,
                                            const float* __restrict__ bc2,
                                            float* __restrict__ out) {
    __shared__ float row[DIM];
    __shared__ float t1[64];
    int g = blockIdx.x, t = threadIdx.x;
    row[t] = pooled[g * DIM + t];
    row[64 + t] = pooled[g * DIM + 64 + t];
    __syncthreads();
    float acc = bc1[t];
    for (int k = 0; k < DIM; k++) acc += row[k] * Wc1[k * 64 + t];
    t1[t] = acc > 0.f ? acc : 0.f;
    __syncthreads();
    if (t < 2) {
        float o = bc2[t];
        for (int j = 0; j < 64; j++) o += t1[j] * Wc2[j * 2 + t];
        out[g * 2 + t] = o;
    }
}

// ============================ launch ============================

extern "C" void kernel_launch(void* const* d_in, const int* in_sizes, int n_in,
                              void* d_out, int out_size, void* d_ws, size_t ws_size,
                              hipStream_t stream) {
    const float* x          = (const float*)d_in[0];
    const int*   edge_index = (const int*)d_in[1];
    const float* edge_attr  = (const float*)d_in[2];
    const int*   batch      = (const int*)d_in[3];
    const float* le1_w = (const float*)d_in[4];
    const float* le1_b = (const float*)d_in[5];
    const float* W11   = (const float*)d_in[6];
    const float* b11   = (const float*)d_in[7];
    const float* g1    = (const float*)d_in[8];
    const float* bt1   = (const float*)d_in[9];
    const float* W12   = (const float*)d_in[10];
    const float* b12   = (const float*)d_in[11];
    const float* le2_w = (const float*)d_in[12];
    const float* le2_b = (const float*)d_in[13];
    const float* W21   = (const float*)d_in[14];
    const float* b21   = (const float*)d_in[15];
    const float* g2    = (const float*)d_in[16];
    const float* bt2   = (const float*)d_in[17];
    const float* W22   = (const float*)d_in[18];
    const float* b22   = (const float*)d_in[19];
    const float* Wc1   = (const float*)d_in[20];
    const float* bc1   = (const float*)d_in[21];
    const float* Wc2   = (const float*)d_in[22];
    const float* bc2   = (const float*)d_in[23];
    float* out = (float*)d_out;

    const int* srcp = edge_index;
    const int* dstp = edge_index + N_EDGES;

    // workspace carve (all offsets 256B aligned)
    char* ws = (char*)d_ws;
    size_t off = 0;
    auto carve = [&](size_t bytes) -> char* {
        char* p = ws + off;
        off += (bytes + 255) & ~(size_t)255;
        return p;
    };
    float* A      = (float*)carve((size_t)N_NODES * DIM * 4);   // agg / h
    float* B      = (float*)carve((size_t)N_NODES * DIM * 4);   // pre-BN hidden
    float* C      = (float*)carve((size_t)N_NODES * DIM * 4);   // layer output
    int*   rowptr = (int*)carve((size_t)(N_NODES + 1) * 4);
    int*   cursor = (int*)carve((size_t)N_NODES * 4);           // also deg
    int*   sums   = (int*)carve(256 * 4);
    int2*  csr    = (int2*)carve((size_t)N_EDGES * 8);
    float* colstat = (float*)carve(2 * DIM * 4);
    float* coef    = (float*)carve(2 * DIM * 4);
    float* pooled  = (float*)carve((size_t)N_GRAPHS * DIM * 4);
    (void)ws_size; (void)in_sizes; (void)n_in; (void)out_size;

    const int nch = (N_NODES + 1023) / 1024;   // 98

    // --- CSR build (reused by both conv layers) ---
    hipMemsetAsync(cursor, 0, (size_t)N_NODES * 4, stream);     // deg = 0
    k_hist<<<(N_EDGES + 255) / 256, 256, 0, stream>>>(dstp, cursor);
    k_scan1<<<nch, 256, 0, stream>>>(cursor, rowptr + 1, sums, N_NODES);
    k_scan2<<<1, 256, 0, stream>>>(sums, nch);
    k_scan3<<<nch, 256, 0, stream>>>(rowptr, cursor, sums, N_NODES);
    k_fill<<<(N_EDGES + 255) / 256, 256, 0, stream>>>(srcp, dstp, cursor, csr);

    // --- layer 1 ---
    k_gine_msg<<<N_NODES / 4, 256, 0, stream>>>(x, edge_attr, rowptr, csr, le1_w, le1_b, A);
    k_gemm<0><<<(N_NODES + 31) / 32, 256, 0, stream>>>(A, W11, b11, nullptr, B, N_NODES);
    hipMemsetAsync(colstat, 0, 2 * DIM * 4, stream);
    k_colstats<<<256, 128, 0, stream>>>(B, colstat, N_NODES);
    k_bncoef<<<1, 128, 0, stream>>>(colstat, g1, bt1, coef);
    k_gemm<1><<<(N_NODES + 31) / 32, 256, 0, stream>>>(B, W12, b12, coef, C, N_NODES);

    // --- layer 2 ---
    k_gine_msg<<<N_NODES / 4, 256, 0, stream>>>(C, edge_attr, rowptr, csr, le2_w, le2_b, A);
    k_gemm<0><<<(N_NODES + 31) / 32, 256, 0, stream>>>(A, W21, b21, nullptr, B, N_NODES);
    hipMemsetAsync(colstat, 0, 2 * DIM * 4, stream);
    k_colstats<<<256, 128, 0, stream>>>(B, colstat, N_NODES);
    k_bncoef<<<1, 128, 0, stream>>>(colstat, g2, bt2, coef);
    k_gemm<1><<<(N_NODES + 31) / 32, 256, 0, stream>>>(B, W22, b22, coef, C, N_NODES);

    // --- pool + classifier ---
    k_pool<<<N_GRAPHS, 128, 0, stream>>>(C, batch, pooled);
    k_cls<<<N_GRAPHS, 64, 0, stream>>>(pooled, Wc1, bc1, Wc2, bc2, out);
}

// Round 4
// 979.232 us; speedup vs baseline: 1.3978x; 1.3978x over previous
//
#include <hip/hip_runtime.h>
#include <hip/hip_fp16.h>

#define N_NODES  100000
#define N_EDGES  1600000
#define N_GRAPHS 512
#define DIM      128
#define EDGE_DIM 16
#define BN_EPS   1e-5f

// ============================ CSR build ============================

__global__ __launch_bounds__(256) void k_hist(const int* __restrict__ dst,
                                              int* __restrict__ deg) {
    int e = blockIdx.x * 256 + threadIdx.x;
    if (e < N_EDGES) atomicAdd(&deg[dst[e]], 1);
}

__global__ __launch_bounds__(256) void k_scan1(const int* __restrict__ deg,
                                               int* __restrict__ rowptr1,
                                               int* __restrict__ sums, int N) {
    __shared__ int sc[256];
    int t = threadIdx.x;
    int base = blockIdx.x * 1024 + t * 4;
    int v0 = (base + 0 < N) ? deg[base + 0] : 0;
    int v1 = (base + 1 < N) ? deg[base + 1] : 0;
    int v2 = (base + 2 < N) ? deg[base + 2] : 0;
    int v3 = (base + 3 < N) ? deg[base + 3] : 0;
    v1 += v0; v2 += v1; v3 += v2;
    sc[t] = v3;
    __syncthreads();
    for (int o = 1; o < 256; o <<= 1) {
        int add = (t >= o) ? sc[t - o] : 0;
        __syncthreads();
        sc[t] += add;
        __syncthreads();
    }
    int prefix = sc[t] - v3;
    if (base + 0 < N) rowptr1[base + 0] = v0 + prefix;
    if (base + 1 < N) rowptr1[base + 1] = v1 + prefix;
    if (base + 2 < N) rowptr1[base + 2] = v2 + prefix;
    if (base + 3 < N) rowptr1[base + 3] = v3 + prefix;
    if (t == 255) sums[blockIdx.x] = sc[255];
}

__global__ __launch_bounds__(256) void k_scan2(int* __restrict__ sums, int n) {
    __shared__ int sc[256];
    int t = threadIdx.x;
    int v = (t < n) ? sums[t] : 0;
    sc[t] = v;
    __syncthreads();
    for (int o = 1; o < 256; o <<= 1) {
        int add = (t >= o) ? sc[t - o] : 0;
        __syncthreads();
        sc[t] += add;
        __syncthreads();
    }
    if (t < n) sums[t] = sc[t];
}

__global__ __launch_bounds__(256) void k_scan3(int* __restrict__ rowptr,
                                               int* __restrict__ cursor,
                                               const int* __restrict__ sums, int N) {
    int c = blockIdx.x;
    int off = (c == 0) ? 0 : sums[c - 1];
    int t = threadIdx.x;
    int base = c * 1024 + t * 4;
#pragma unroll
    for (int i = 0; i < 4; i++) {
        int g = base + i;
        if (g < N) {
            int val = rowptr[1 + g] + off;
            rowptr[1 + g] = val;
            if (g + 1 < N) cursor[g + 1] = val;
        }
    }
    if (c == 0 && t == 0) { rowptr[0] = 0; cursor[0] = 0; }
}

// fill CSR: src index + gather edge_attr row (converted to fp16) into CSR order
__global__ __launch_bounds__(256) void k_fill(const int* __restrict__ src,
                                              const int* __restrict__ dst,
                                              const float* __restrict__ edge_attr,
                                              int* __restrict__ cursor,
                                              int* __restrict__ csr_src,
                                              uint4* __restrict__ csr_ea) {
    int e = blockIdx.x * 256 + threadIdx.x;
    if (e < N_EDGES) {
        int d = dst[e];
        int p = atomicAdd(&cursor[d], 1);
        csr_src[p] = src[e];
        const float4* ea = (const float4*)(edge_attr + (size_t)e * EDGE_DIM);
        float4 a0 = ea[0], a1 = ea[1], a2 = ea[2], a3 = ea[3];
        union { __half h[16]; uint4 q[2]; } u;
        u.h[0]  = __float2half(a0.x); u.h[1]  = __float2half(a0.y);
        u.h[2]  = __float2half(a0.z); u.h[3]  = __float2half(a0.w);
        u.h[4]  = __float2half(a1.x); u.h[5]  = __float2half(a1.y);
        u.h[6]  = __float2half(a1.z); u.h[7]  = __float2half(a1.w);
        u.h[8]  = __float2half(a2.x); u.h[9]  = __float2half(a2.y);
        u.h[10] = __float2half(a2.z); u.h[11] = __float2half(a2.w);
        u.h[12] = __float2half(a3.x); u.h[13] = __float2half(a3.y);
        u.h[14] = __float2half(a3.z); u.h[15] = __float2half(a3.w);
        uint4* o = csr_ea + (size_t)p * 2;
        o[0] = u.q[0]; o[1] = u.q[1];
    }
}

// ==================== GINE message + aggregate ====================
// One wave per node; lane owns features {2*lane, 2*lane+1} (float2 layout).
// agg[node] = x[node] + sum_e relu(x[src_e] + ea_e @ le_w + le_b)
__device__ __forceinline__ void edge_acc(float2 xr, uint4 q0, uint4 q1,
                                         const float* wl0, const float* wl1,
                                         float b0, float b1,
                                         float& acc0, float& acc1) {
    union { uint4 q[2]; __half h[16]; } u;
    u.q[0] = q0; u.q[1] = q1;
    float e0 = b0, e1 = b1;
#pragma unroll
    for (int k = 0; k < 16; k++) {
        float a = __half2float(u.h[k]);
        e0 = fmaf(a, wl0[k], e0);
        e1 = fmaf(a, wl1[k], e1);
    }
    acc0 += fmaxf(xr.x + e0, 0.f);
    acc1 += fmaxf(xr.y + e1, 0.f);
}

__global__ __launch_bounds__(256) void k_gine_msg(const float* __restrict__ x,
                                                  const uint4* __restrict__ csr_ea,
                                                  const int* __restrict__ rowptr,
                                                  const int* __restrict__ csr_src,
                                                  const float* __restrict__ lew,
                                                  const float* __restrict__ leb,
                                                  float* __restrict__ agg) {
    int lane = threadIdx.x & 63;
    int node = blockIdx.x * 4 + (threadIdx.x >> 6);
    int f0 = lane * 2;

    float wl0[EDGE_DIM], wl1[EDGE_DIM];
#pragma unroll
    for (int k = 0; k < EDGE_DIM; k++) {
        wl0[k] = lew[k * DIM + f0];
        wl1[k] = lew[k * DIM + f0 + 1];
    }
    float b0 = leb[f0], b1 = leb[f0 + 1];

    float2 xv = *(const float2*)(x + (size_t)node * DIM + f0);
    float acc0 = xv.x, acc1 = xv.y;

    int pbeg = __builtin_amdgcn_readfirstlane(rowptr[node]);
    int pend = __builtin_amdgcn_readfirstlane(rowptr[node + 1]);

    int p = pbeg;
    for (; p + 4 <= pend; p += 4) {
        int s0 = __builtin_amdgcn_readfirstlane(csr_src[p + 0]);
        int s1 = __builtin_amdgcn_readfirstlane(csr_src[p + 1]);
        int s2 = __builtin_amdgcn_readfirstlane(csr_src[p + 2]);
        int s3 = __builtin_amdgcn_readfirstlane(csr_src[p + 3]);

        const uint4* ea = csr_ea + (size_t)p * 2;
        uint4 a00 = ea[0], a01 = ea[1];
        uint4 a10 = ea[2], a11 = ea[3];
        uint4 a20 = ea[4], a21 = ea[5];
        uint4 a30 = ea[6], a31 = ea[7];

        float2 x0 = *(const float2*)(x + (size_t)s0 * DIM + f0);
        float2 x1 = *(const float2*)(x + (size_t)s1 * DIM + f0);
        float2 x2 = *(const float2*)(x + (size_t)s2 * DIM + f0);
        float2 x3 = *(const float2*)(x + (size_t)s3 * DIM + f0);

        edge_acc(x0, a00, a01, wl0, wl1, b0, b1, acc0, acc1);
        edge_acc(x1, a10, a11, wl0, wl1, b0, b1, acc0, acc1);
        edge_acc(x2, a20, a21, wl0, wl1, b0, b1, acc0, acc1);
        edge_acc(x3, a30, a31, wl0, wl1, b0, b1, acc0, acc1);
    }
    for (; p < pend; p++) {
        int s0 = __builtin_amdgcn_readfirstlane(csr_src[p]);
        const uint4* ea = csr_ea + (size_t)p * 2;
        uint4 a0 = ea[0], a1 = ea[1];
        float2 x0 = *(const float2*)(x + (size_t)s0 * DIM + f0);
        edge_acc(x0, a0, a1, wl0, wl1, b0, b1, acc0, acc1);
    }

    float2 o; o.x = acc0; o.y = acc1;
    *(float2*)(agg + (size_t)node * DIM + f0) = o;
}

// ======================= node GEMM (M x 128 @ 128 x 128) =======================
// MODE 0: out = A @ W + bias
// MODE 1: out = relu( relu(a*A+c) @ W + bias )
template <int MODE>
__global__ __launch_bounds__(256) void k_gemm(const float* __restrict__ A,
                                              const float* __restrict__ W,
                                              const float* __restrict__ bias,
                                              const float* __restrict__ coef,
                                              float* __restrict__ out, int M) {
    __shared__ float As[32][DIM];
    int t = threadIdx.x;
    int rbase = blockIdx.x * 32;

#pragma unroll
    for (int i = 0; i < 16; i++) {
        int idx = t + i * 256;
        int r = idx >> 7, c = idx & 127;
        int gr = rbase + r;
        float v = (gr < M) ? A[(size_t)gr * DIM + c] : 0.f;
        if (MODE == 1) {
            v = coef[c] * v + coef[DIM + c];
            v = v > 0.f ? v : 0.f;
        }
        As[r][c] = v;
    }
    __syncthreads();

    int cq = (t & 31) * 4;
    int rg = (t >> 5) * 4;
    float acc[4][4] = {{0.f}};

    for (int k = 0; k < DIM; k++) {
        float4 w = *(const float4*)&W[(size_t)k * DIM + cq];
        float a0 = As[rg + 0][k], a1 = As[rg + 1][k];
        float a2 = As[rg + 2][k], a3 = As[rg + 3][k];
        acc[0][0] += a0 * w.x; acc[0][1] += a0 * w.y; acc[0][2] += a0 * w.z; acc[0][3] += a0 * w.w;
        acc[1][0] += a1 * w.x; acc[1][1] += a1 * w.y; acc[1][2] += a1 * w.z; acc[1][3] += a1 * w.w;
        acc[2][0] += a2 * w.x; acc[2][1] += a2 * w.y; acc[2][2] += a2 * w.z; acc[2][3] += a2 * w.w;
        acc[3][0] += a3 * w.x; acc[3][1] += a3 * w.y; acc[3][2] += a3 * w.z; acc[3][3] += a3 * w.w;
    }

    float4 bb = *(const float4*)&bias[cq];
#pragma unroll
    for (int i = 0; i < 4; i++) {
        int gr = rbase + rg + i;
        if (gr < M) {
            float4 o;
            o.x = acc[i][0] + bb.x;
            o.y = acc[i][1] + bb.y;
            o.z = acc[i][2] + bb.z;
            o.w = acc[i][3] + bb.w;
            if (MODE == 1) {
                o.x = o.x > 0.f ? o.x : 0.f;
                o.y = o.y > 0.f ? o.y : 0.f;
                o.z = o.z > 0.f ? o.z : 0.f;
                o.w = o.w > 0.f ? o.w : 0.f;
            }
            *(float4*)&out[(size_t)gr * DIM + cq] = o;
        }
    }
}

// ===================== BN column statistics =====================
__global__ __launch_bounds__(512) void k_colstats(const float* __restrict__ h,
                                                  float* __restrict__ colstat, int M) {
    __shared__ float redS[4][DIM];
    __shared__ float redQ[4][DIM];
    int c = threadIdx.x & 127;
    int rg = threadIdx.x >> 7;
    float s = 0.f, ss = 0.f;
    for (int r = blockIdx.x * 4 + rg; r < M; r += gridDim.x * 4) {
        float v = h[(size_t)r * DIM + c];
        s += v;
        ss += v * v;
    }
    redS[rg][c] = s; redQ[rg][c] = ss;
    __syncthreads();
    if (rg == 0) {
        s  = redS[0][c] + redS[1][c] + redS[2][c] + redS[3][c];
        ss = redQ[0][c] + redQ[1][c] + redQ[2][c] + redQ[3][c];
        atomicAdd(&colstat[c], s);
        atomicAdd(&colstat[DIM + c], ss);
    }
}

__global__ __launch_bounds__(128) void k_bncoef(const float* __restrict__ colstat,
                                                const float* __restrict__ gamma,
                                                const float* __restrict__ beta,
                                                float* __restrict__ coef) {
    int c = threadIdx.x;
    float inv_n = 1.f / (float)N_NODES;
    float mean = colstat[c] * inv_n;
    float var = colstat[DIM + c] * inv_n - mean * mean;
    float a = gamma[c] * rsqrtf(var + BN_EPS);
    coef[c] = a;
    coef[DIM + c] = beta[c] - mean * a;
}

// ===================== global add pool (batch is sorted) =====================
__global__ __launch_bounds__(256) void k_pool(const float* __restrict__ h,
                                              const int* __restrict__ batch,
                                              float* __restrict__ pooled) {
    __shared__ float red[DIM];
    int g = blockIdx.x;
    int c = threadIdx.x & 127;
    int rg = threadIdx.x >> 7;
    int lo = 0, hi = N_NODES;
    while (lo < hi) { int mid = (lo + hi) >> 1; if (batch[mid] < g) lo = mid + 1; else hi = mid; }
    int start = lo;
    hi = N_NODES;
    while (lo < hi) { int mid = (lo + hi) >> 1; if (batch[mid] < g + 1) lo = mid + 1; else hi = mid; }
    int end = lo;
    float s = 0.f;
    for (int n = start + rg; n < end; n += 2) s += h[(size_t)n * DIM + c];
    if (rg == 1) red[c] = s;
    __syncthreads();
    if (rg == 0) pooled[g * DIM + c] = s + red[c];
}

// ===================== classifier =====================
__global__ __launch_bounds__(64) void k_cls(const float* __restrict__ pooled,
                                            const float* __restrict__ Wc1,
                                            const float* __restrict__ bc1,
                                            const float* __restrict__ Wc2,
                                            const float* __restrict__ bc2,
                                            float* __restrict__ out) {
    __shared__ float row[DIM];
    __shared__ float t1[64];
    int g = blockIdx.x, t = threadIdx.x;
    row[t] = pooled[g * DIM + t];
    row[64 + t] = pooled[g * DIM + 64 + t];
    __syncthreads();
    float acc = bc1[t];
    for (int k = 0; k < DIM; k++) acc += row[k] * Wc1[k * 64 + t];
    t1[t] = acc > 0.f ? acc : 0.f;
    __syncthreads();
    if (t < 2) {
        float o = bc2[t];
        for (int j = 0; j < 64; j++) o += t1[j] * Wc2[j * 2 + t];
        out[g * 2 + t] = o;
    }
}

// ============================ launch ============================

extern "C" void kernel_launch(void* const* d_in, const int* in_sizes, int n_in,
                              void* d_out, int out_size, void* d_ws, size_t ws_size,
                              hipStream_t stream) {
    const float* x          = (const float*)d_in[0];
    const int*   edge_index = (const int*)d_in[1];
    const float* edge_attr  = (const float*)d_in[2];
    const int*   batch      = (const int*)d_in[3];
    const float* le1_w = (const float*)d_in[4];
    const float* le1_b = (const float*)d_in[5];
    const float* W11   = (const float*)d_in[6];
    const float* b11   = (const float*)d_in[7];
    const float* g1    = (const float*)d_in[8];
    const float* bt1   = (const float*)d_in[9];
    const float* W12   = (const float*)d_in[10];
    const float* b12   = (const float*)d_in[11];
    const float* le2_w = (const float*)d_in[12];
    const float* le2_b = (const float*)d_in[13];
    const float* W21   = (const float*)d_in[14];
    const float* b21   = (const float*)d_in[15];
    const float* g2    = (const float*)d_in[16];
    const float* bt2   = (const float*)d_in[17];
    const float* W22   = (const float*)d_in[18];
    const float* b22   = (const float*)d_in[19];
    const float* Wc1   = (const float*)d_in[20];
    const float* bc1   = (const float*)d_in[21];
    const float* Wc2   = (const float*)d_in[22];
    const float* bc2   = (const float*)d_in[23];
    float* out = (float*)d_out;

    const int* srcp = edge_index;
    const int* dstp = edge_index + N_EDGES;

    char* ws = (char*)d_ws;
    size_t off = 0;
    auto carve = [&](size_t bytes) -> char* {
        char* p = ws + off;
        off += (bytes + 255) & ~(size_t)255;
        return p;
    };
    float* X0      = (float*)carve((size_t)N_NODES * DIM * 4);   // 51.2 MB
    float* X1      = (float*)carve((size_t)N_NODES * DIM * 4);   // 51.2 MB
    int*   rowptr  = (int*)carve((size_t)(N_NODES + 1) * 4);
    int*   cursor  = (int*)carve((size_t)N_NODES * 4);           // also deg
    int*   sums    = (int*)carve(256 * 4);
    int*   csr_src = (int*)carve((size_t)N_EDGES * 4);           // 6.4 MB
    uint4* csr_ea  = (uint4*)carve((size_t)N_EDGES * 32);        // fp16, 51.2 MB
    float* colstat = (float*)carve(2 * DIM * 4);
    float* coef    = (float*)carve(2 * DIM * 4);
    float* pooled  = (float*)carve((size_t)N_GRAPHS * DIM * 4);
    (void)ws_size; (void)in_sizes; (void)n_in; (void)out_size;

    const int nch = (N_NODES + 1023) / 1024;   // 98

    // --- CSR build + fp16 edge_attr gather (reused by both conv layers) ---
    hipMemsetAsync(cursor, 0, (size_t)N_NODES * 4, stream);
    k_hist<<<(N_EDGES + 255) / 256, 256, 0, stream>>>(dstp, cursor);
    k_scan1<<<nch, 256, 0, stream>>>(cursor, rowptr + 1, sums, N_NODES);
    k_scan2<<<1, 256, 0, stream>>>(sums, nch);
    k_scan3<<<nch, 256, 0, stream>>>(rowptr, cursor, sums, N_NODES);
    k_fill<<<(N_EDGES + 255) / 256, 256, 0, stream>>>(srcp, dstp, edge_attr, cursor,
                                                      csr_src, csr_ea);

    // --- layer 1 ---
    k_gine_msg<<<N_NODES / 4, 256, 0, stream>>>(x, csr_ea, rowptr, csr_src, le1_w, le1_b, X0);
    k_gemm<0><<<(N_NODES + 31) / 32, 256, 0, stream>>>(X0, W11, b11, nullptr, X1, N_NODES);
    hipMemsetAsync(colstat, 0, 2 * DIM * 4, stream);
    k_colstats<<<256, 512, 0, stream>>>(X1, colstat, N_NODES);
    k_bncoef<<<1, 128, 0, stream>>>(colstat, g1, bt1, coef);
    k_gemm<1><<<(N_NODES + 31) / 32, 256, 0, stream>>>(X1, W12, b12, coef, X0, N_NODES);

    // --- layer 2 ---
    k_gine_msg<<<N_NODES / 4, 256, 0, stream>>>(X0, csr_ea, rowptr, csr_src, le2_w, le2_b, X1);
    k_gemm<0><<<(N_NODES + 31) / 32, 256, 0, stream>>>(X1, W21, b21, nullptr, X0, N_NODES);
    hipMemsetAsync(colstat, 0, 2 * DIM * 4, stream);
    k_colstats<<<256, 512, 0, stream>>>(X0, colstat, N_NODES);
    k_bncoef<<<1, 128, 0, stream>>>(colstat, g2, bt2, coef);
    k_gemm<1><<<(N_NODES + 31) / 32, 256, 0, stream>>>(X0, W22, b22, coef, X1, N_NODES);

    // --- pool + classifier ---
    k_pool<<<N_GRAPHS, 256, 0, stream>>>(X1, batch, pooled);
    k_cls<<<N_GRAPHS, 64, 0, stream>>>(pooled, Wc1, bc1, Wc2, bc2, out);
}